// Round 1
// 168.233 us; speedup vs baseline: 1.0167x; 1.0167x over previous
//
#include <hip/hip_runtime.h>

// FilteredNoiseGenerator: B=32, t=4000, nbands=65, framesize=80, L_fir=129, L=208
// out[b,p] = sum_{f,m} x[b,f,m]*w[b,f,tau], tau = (p+64) - 80f - m in [0,128]
// P1 (firwin) = GEMM vs fixed matrix M (MFMA f16, M in d_ws, frag-order).
// R9: VALU-overhead attack (kernel was VALU-issue-bound: 64% busy, only ~15% of
//     issued VALU = fdot2). Changes vs R8:
//     - x stored REVERSED in its own LDS region (xr[u] = x[79-u]): descending
//       m-pairs for fdot2 come straight out of aligned b64 loads, no alignbit
//       swaps. Bit-identical summation order preserved.
//     - P2 trips process 8 m-values (2x ds_read_b64 x, 40 fdot2, slide 4 w-pair
//       slots); unroll 4 -> window shift is pure register renaming.
//     - P1.5 re-park pass and 3rd barrier deleted (P0 stages x directly).
//     - H staging in 4-element units w/ zero-fill only where needed; rows >=35
//       left garbage (their MFMA rows are discarded by the frame<NSLOT guard).

#define NT 256
#define X_STRIDE 84        // f16 x row stride; 168 B rows (8B-aligned), 42 dw -> 2-way banks (free)
#define W_STRIDE 158       // f16 w row; 79 dw/row, gcd(79,32)=1 -> conflict-free
#define W_P 18             // w[tau] at wr[W_P+tau]; tau in [0,128]; zeros outside
#define NSLOT 35           // frames f0-2 .. f0+32
#define WTOT_H 5544        // >= 34*158 + 168 (max windowed read spills into pads)
#define HF_STRIDE 104      // f16 H row stride (208 B, 16B-aligned b128 frag loads)
#define HTOT_H 4992        // 48*104 (rows 35..47 read-garbage, discarded)
#define XTOT_H 2940        // 35*84

typedef _Float16 f16x8 __attribute__((ext_vector_type(8)));
typedef _Float16 f16x4 __attribute__((ext_vector_type(4)));
typedef _Float16 h2 __attribute__((ext_vector_type(2)));
typedef float f32x4 __attribute__((ext_vector_type(4)));

union U32H2 { unsigned u; h2 h; };
static __device__ __forceinline__ h2 mid_h2(h2 lo, h2 hi) {    // (lo.y, hi.x)
  U32H2 a, b; a.h = lo; b.h = hi;
  U32H2 o; o.u = __builtin_amdgcn_alignbit(b.u, a.u, 16);
  return o.h;
}

// ---- init: M in MFMA B-operand frag order (R6-proven). frag (nt,ks) of 27;
// lane holds B[k = ks*32 + (lane>>4)*8 + j][n = nt*16 + (lane&15)], j=0..7.
__global__ void __launch_bounds__(256)
minit_kernel(_Float16* __restrict__ M) {
  const float TP = 6.28318530717958647692f / 129.f;
  int i = blockIdx.x * 256 + threadIdx.x;      // 54*256 = 13824 = 27*512 exactly
  int frag = i >> 9;
  int off  = i & 511;
  int lane = off >> 3, j = off & 7;
  int nt = frag / 3, ks = frag - 3 * (frag / 3);
  int n = nt * 16 + (lane & 15);
  int k = ks * 32 + (lane >> 4) * 8 + j;
  float v = 0.f;
  if (n <= 128 && k <= 64) {
    float hann = 0.5f - 0.5f * __cosf((float)n * TP);
    float sc = (k == 0 ? 1.f : 2.f) * (1.f / 129.f);
    int e = (k * (n - 64)) % 129; if (e < 0) e += 129;   // exact arg reduction
    v = hann * sc * __cosf((float)e * TP);
  }
  M[i] = (_Float16)v;
}

__global__ void __launch_bounds__(NT)
fng_kernel(const float* __restrict__ Hg_, const float* __restrict__ Ng_,
           float* __restrict__ Og_, const _Float16* __restrict__ Mg) {
  __shared__ __align__(16) _Float16 sWh[WTOT_H];   // 11,088 B firwin f16, zero-padded
  __shared__ __align__(16) _Float16 sXh[XTOT_H];   //  5,880 B x f16, REVERSED rows
  __shared__ __align__(16) _Float16 sHf[HTOT_H];   //  9,984 B H f16 (P1 A-operand)

  const int t  = threadIdx.x;
  const int bx = blockIdx.x;     // 0..124 (32 output-frames each)
  const int b  = blockIdx.y;     // 0..31
  const int f0 = bx * 32;

  // ---------------- P0a: zero sWh (data overwritten by P1; pads stay 0) ----
  {
    float4 z4 = {0.f, 0.f, 0.f, 0.f};
    for (int i = t; i < WTOT_H / 8; i += NT) ((float4*)sWh)[i] = z4;
  }

  // ---------------- P0b: H -> f16 LDS, 4-elem units ----------------
  // 35 rows x 24 units: u<16 data quad, u==16 tail (k=64 + zeros 65..67),
  // u in [17,24) zero quads k=68..95. Rows >=35 untouched (garbage, discarded).
  {
    const float* Hg = Hg_ + (size_t)b * (4000 * 65);
#pragma unroll
    for (int j = 0; j < 4; ++j) {
      int i = t + NT * j;
      if (i < 35 * 24) {
        int r = i / 24, u = i - 24 * r;
        int fr = f0 - 2 + r;
        f16x4 o = {(_Float16)0.f, (_Float16)0.f, (_Float16)0.f, (_Float16)0.f};
        if (u < 16) {
          if (fr >= 0 && fr < 4000) {
            const float* hp = &Hg[fr * 65 + 4 * u];
            o.x = (_Float16)hp[0]; o.y = (_Float16)hp[1];
            o.z = (_Float16)hp[2]; o.w = (_Float16)hp[3];
          }
          *(f16x4*)&sHf[r * HF_STRIDE + 4 * u] = o;
        } else if (u == 16) {
          if (fr >= 0 && fr < 4000) o.x = (_Float16)Hg[fr * 65 + 64];
          *(f16x4*)&sHf[r * HF_STRIDE + 64] = o;     // k=64 + zeros 65..67
        } else {
          *(f16x4*)&sHf[r * HF_STRIDE + 4 * u] = o;  // zeros k=68..95
        }
      }
    }
  }

  // ---------------- P0c: noise -> sXh REVERSED f16 (xr[u] = 2*noise[79-u]-1) --
  {
    const float* Ng = Ng_ + (size_t)b * 320000;
#pragma unroll
    for (int j = 0; j < 3; ++j) {
      int q = t + NT * j;
      if (q < NSLOT * 20) {
        int fi = q / 20, qm = q - 20 * fi;
        int fr = f0 - 2 + fi;
        f16x4 o = {(_Float16)0.f, (_Float16)0.f, (_Float16)0.f, (_Float16)0.f};
        if (fr >= 0 && fr < 4000) {
          float4 v = *(const float4*)&Ng[(size_t)fr * 80 + 4 * qm];
          o.x = (_Float16)(2.f * v.w - 1.f);   // x[4qm+3]
          o.y = (_Float16)(2.f * v.z - 1.f);   // x[4qm+2]
          o.z = (_Float16)(2.f * v.y - 1.f);   // x[4qm+1]
          o.w = (_Float16)(2.f * v.x - 1.f);   // x[4qm]
        }
        *(f16x4*)&sXh[fi * X_STRIDE + (76 - 4 * qm)] = o;   // 8B-aligned
      }
    }
  }
  __syncthreads();

  // ------- P1: firwin = H x M^T via MFMA 16x16x32 f16 (R6-proven layout) -------
  {
    const int wv   = t >> 6;
    const int lane = t & 63;
    const int quad = lane >> 4;
    const int l15  = lane & 15;
#pragma unroll 1
    for (int tile = wv; tile < 27; tile += 4) {
      const int mt = tile / 9, nt = tile - 9 * (tile / 9);
      f32x4 acc = {0.f, 0.f, 0.f, 0.f};
#pragma unroll
      for (int ks = 0; ks < 3; ++ks) {
        f16x8 a = *(const f16x8*)&sHf[(mt * 16 + l15) * HF_STRIDE + ks * 32 + quad * 8];
        f16x8 bb = ((const f16x8*)Mg)[(nt * 3 + ks) * 64 + lane];
        acc = __builtin_amdgcn_mfma_f32_16x16x32_f16(a, bb, acc, 0, 0, 0);
      }
      const int n = nt * 16 + l15;
      const int fr0 = mt * 16 + quad * 4;
      if (n <= 128) {
#pragma unroll
        for (int r = 0; r < 4; ++r) {
          int frame = fr0 + r;
          if (frame < NSLOT) sWh[frame * W_STRIDE + W_P + n] = (_Float16)acc[r];
        }
      }
    }
  }
  __syncthreads();

  // ------- P2: gather convolution, 8-m-wide trips, reversed-x (no swaps) -------
  {
    const int col = t & 31;
    const int pb  = t >> 5;
    const int e   = 64 + 10 * pb;
    const int qq  = (e >= 80) ? 1 : 0;
    const int D   = e - 80 * qq;                    // per half-wave uniform, even
    float acc[10];
#pragma unroll
    for (int i = 0; i < 10; ++i) acc[i] = 0.f;

#pragma unroll 1
    for (int g = 2; g >= -1; --g) {                 // source frame F - g
      const int dlt = D + 80 * g;                   // even
      int Ulo = (dlt - 128) >> 3; if (Ulo < 0) Ulo = 0;   // ceil((dlt-135)/8)
      int Uhi = (dlt + 9) >> 3;   if (Uhi > 9) Uhi = 9;
      if (Ulo > Uhi) continue;
      const int slot = col + qq - g + 2;            // 0..33 (34 never active)
      const _Float16* wr = &sWh[slot * W_STRIDE];
      const _Float16* xr = &sXh[slot * X_STRIDE];
      int wb = W_P + dlt - 8 * Ulo - 4;             // even; running tap base

      // w-window: wEa[k] = (w[wb-4+2k], w[wb-4+2k+1]) even-aligned b32 loads,
      // wOa[k] = odd pair via alignbit. PAIR(K)=(wr[wb+K], wr[wb+K+1]),
      // K in [-3,13] used. All out-of-range taps land in zero pads.
      h2 wEa[10], wOa[9];
#pragma unroll
      for (int k2 = 0; k2 < 10; ++k2) wEa[k2] = *(const h2*)&wr[wb - 4 + 2 * k2];
#pragma unroll
      for (int k2 = 0; k2 < 9; ++k2) wOa[k2] = mid_h2(wEa[k2], wEa[k2 + 1]);

#define PAIRX(K) (((K) & 1) ? wOa[(((K) - 1) >> 1) + 2] : wEa[(((K) >> 1) + 2)])
#pragma unroll 4
      for (int U = Ulo; U <= Uhi; ++U) {
        // reversed rows: xr[u]=x[79-u] -> aligned b64s give descending pairs free
        const _Float16* xp = &xr[72 - 8 * U];
        f16x4 q0 = *(const f16x4*)&xp[0];           // (x7,x6,x5,x4) of m=8U+..
        f16x4 q1 = *(const f16x4*)&xp[4];           // (x3,x2,x1,x0)
        h2 xD; xD.x = q0.x; xD.y = q0.y;            // (x7,x6) — reg halves, free
        h2 xC; xC.x = q0.z; xC.y = q0.w;            // (x5,x4)
        h2 xB; xB.x = q1.x; xB.y = q1.y;            // (x3,x2)
        h2 xA; xA.x = q1.z; xA.y = q1.w;            // (x1,x0)
#pragma unroll
        for (int i = 0; i < 10; ++i) {
          float a = acc[i];
          a = __builtin_amdgcn_fdot2(xA, PAIRX(i + 3), a, false);  // m 8U+0,1
          a = __builtin_amdgcn_fdot2(xB, PAIRX(i + 1), a, false);  // m 8U+2,3
          a = __builtin_amdgcn_fdot2(xC, PAIRX(i - 1), a, false);  // m 8U+4,5
          a = __builtin_amdgcn_fdot2(xD, PAIRX(i - 3), a, false);  // m 8U+6,7
          acc[i] = a;
        }
        // slide window down 8 f16 = 4 pair-slots (unroll-4 renames the shifts)
        int wl = wb - 12; if (wl < 0) wl = 0;       // clamped; pads are zeros
        const _Float16* wp = &wr[wl];
#pragma unroll
        for (int k2 = 9; k2 >= 4; --k2) wEa[k2] = wEa[k2 - 4];
#pragma unroll
        for (int k2 = 8; k2 >= 4; --k2) wOa[k2] = wOa[k2 - 4];
        wEa[0] = *(const h2*)&wp[0];
        wEa[1] = *(const h2*)&wp[2];
        wEa[2] = *(const h2*)&wp[4];
        wEa[3] = *(const h2*)&wp[6];
        wOa[0] = mid_h2(wEa[0], wEa[1]);
        wOa[1] = mid_h2(wEa[1], wEa[2]);
        wOa[2] = mid_h2(wEa[2], wEa[3]);
        wOa[3] = mid_h2(wEa[3], wEa[4]);
        wb -= 8;
      }
#undef PAIRX
    }

    // exactly-once writeout: u0 = 80*col + 10*pb (even -> float2 stores)
    float* Ob = Og_ + (size_t)b * 320000 + 2560 * bx + 80 * col + 10 * pb;
#pragma unroll
    for (int s = 0; s < 5; ++s) {
      float2 v; v.x = acc[2 * s]; v.y = acc[2 * s + 1];
      *(float2*)&Ob[2 * s] = v;
    }
  }
}

extern "C" void kernel_launch(void* const* d_in, const int* in_sizes, int n_in,
                              void* d_out, int out_size, void* d_ws, size_t ws_size,
                              hipStream_t stream) {
  const float* H     = (const float*)d_in[0];   // [32,4000,65] fp32
  const float* noise = (const float*)d_in[1];   // [32,4000,80] fp32
  float* out = (float*)d_out;                   // [32,320000] fp32
  _Float16* M = (_Float16*)d_ws;                // 27,648 B of scratch
  (void)in_sizes; (void)n_in; (void)ws_size; (void)out_size;

  minit_kernel<<<54, 256, 0, stream>>>(M);      // rebuilt every call (ws re-poisoned)
  dim3 grid(125, 32, 1);
  fng_kernel<<<grid, NT, 0, stream>>>(H, noise, out, M);
}

// Round 2
// 158.209 us; speedup vs baseline: 1.0812x; 1.0634x over previous
//
#include <hip/hip_runtime.h>

// FilteredNoiseGenerator: B=32, t=4000, nbands=65, framesize=80, L_fir=129, L=208
// out[b,p] = sum_{f,m} x[b,f,m]*w[b,f,tau], tau = (p+64) - 80f - m in [0,128]
// P1 (firwin) = GEMM vs fixed matrix M (MFMA f16, M in d_ws, frag-order).
// R10: occupancy attack (R9 was latency-bound: 52% VALUBusy, 46% occ, dur flat
//     despite -19% inst). Cut LDS 26,952 -> 21,720 B => 7 blocks/CU (was 6):
//     - sHf: 35 rows (A-row clamped to 34; rows>=35 feed discarded C rows only),
//       stride 72 (cols 0..71 only; ks==2/quad>0 A-frags read a 16B zero stub
//       since M rows k>=65 are zero -- NaN-safe). 9,984 -> 5,056 B.
//     - sWh: W_STRIDE 154 (77 dw, gcd(77,32)=1 conflict-free), W_P 24 ->
//       slide base wb-12 >= 0 for all active (dlt,U): per-trip clamp deleted.
//     - __launch_bounds__(256,7) pins 7 blocks/CU (28 waves, VGPR cap 72).

#define NT 256
#define X_STRIDE 84        // f16 x row stride; 168 B rows (8B-aligned), 42 dw -> 2-way banks (free)
#define W_STRIDE 154       // f16 w row; 77 dw/row, gcd(77,32)=1 -> conflict-free
#define W_P 24             // w[tau] at wr[W_P+tau]; tau in [0,128]; zeros outside
#define NSLOT 35           // frames f0-2 .. f0+32
#define WTOT_H 5392        // >= 34*154 + 153 (max write 5388; max read 5344 incl pads)
#define HF_STRIDE 72       // f16 H row stride (144 B, 16B-aligned b128 frag loads)
#define HROWS 35
#define ZSTUB 2520         // 35*72; 16B-aligned zero stub for k>=72 A-frags
#define HTOT_H 2528        // 35*72 + 8
#define XTOT_H 2940        // 35*84

typedef _Float16 f16x8 __attribute__((ext_vector_type(8)));
typedef _Float16 f16x4 __attribute__((ext_vector_type(4)));
typedef _Float16 h2 __attribute__((ext_vector_type(2)));
typedef float f32x4 __attribute__((ext_vector_type(4)));

union U32H2 { unsigned u; h2 h; };
static __device__ __forceinline__ h2 mid_h2(h2 lo, h2 hi) {    // (lo.y, hi.x)
  U32H2 a, b; a.h = lo; b.h = hi;
  U32H2 o; o.u = __builtin_amdgcn_alignbit(b.u, a.u, 16);
  return o.h;
}

// ---- init: M in MFMA B-operand frag order (R6-proven). frag (nt,ks) of 27;
// lane holds B[k = ks*32 + (lane>>4)*8 + j][n = nt*16 + (lane&15)], j=0..7.
__global__ void __launch_bounds__(256)
minit_kernel(_Float16* __restrict__ M) {
  const float TP = 6.28318530717958647692f / 129.f;
  int i = blockIdx.x * 256 + threadIdx.x;      // 54*256 = 13824 = 27*512 exactly
  int frag = i >> 9;
  int off  = i & 511;
  int lane = off >> 3, j = off & 7;
  int nt = frag / 3, ks = frag - 3 * (frag / 3);
  int n = nt * 16 + (lane & 15);
  int k = ks * 32 + (lane >> 4) * 8 + j;
  float v = 0.f;
  if (n <= 128 && k <= 64) {
    float hann = 0.5f - 0.5f * __cosf((float)n * TP);
    float sc = (k == 0 ? 1.f : 2.f) * (1.f / 129.f);
    int e = (k * (n - 64)) % 129; if (e < 0) e += 129;   // exact arg reduction
    v = hann * sc * __cosf((float)e * TP);
  }
  M[i] = (_Float16)v;
}

__global__ void __launch_bounds__(NT, 7)
fng_kernel(const float* __restrict__ Hg_, const float* __restrict__ Ng_,
           float* __restrict__ Og_, const _Float16* __restrict__ Mg) {
  __shared__ __align__(16) _Float16 sWh[WTOT_H];   // 10,784 B firwin f16, zero-padded
  __shared__ __align__(16) _Float16 sXh[XTOT_H];   //  5,880 B x f16, REVERSED rows
  __shared__ __align__(16) _Float16 sHf[HTOT_H];   //  5,056 B H f16 (P1 A-operand)

  const int t  = threadIdx.x;
  const int bx = blockIdx.x;     // 0..124 (32 output-frames each)
  const int b  = blockIdx.y;     // 0..31
  const int f0 = bx * 32;

  // ---------------- P0a: zero sWh (data overwritten by P1; pads stay 0) ----
  {
    float4 z4 = {0.f, 0.f, 0.f, 0.f};
    for (int i = t; i < WTOT_H / 8; i += NT) ((float4*)sWh)[i] = z4;
    if (t == 0) *(float4*)&sHf[ZSTUB] = z4;        // 16B zero stub (k>=72 A-frags)
  }

  // ---------------- P0b: H -> f16 LDS, 4-elem units (35 rows x 18 units) ----
  // u<16: data quad (cols 4u..4u+3 <= 63); u==16: col 64 + zeros 65..67;
  // u==17: zeros 68..71.
  {
    const float* Hg = Hg_ + (size_t)b * (4000 * 65);
#pragma unroll
    for (int j = 0; j < 3; ++j) {
      int i = t + NT * j;
      if (i < 35 * 18) {
        int r = i / 18, u = i - 18 * r;
        int fr = f0 - 2 + r;
        f16x4 o = {(_Float16)0.f, (_Float16)0.f, (_Float16)0.f, (_Float16)0.f};
        if (u < 16) {
          if (fr >= 0 && fr < 4000) {
            const float* hp = &Hg[fr * 65 + 4 * u];
            o.x = (_Float16)hp[0]; o.y = (_Float16)hp[1];
            o.z = (_Float16)hp[2]; o.w = (_Float16)hp[3];
          }
          *(f16x4*)&sHf[r * HF_STRIDE + 4 * u] = o;
        } else if (u == 16) {
          if (fr >= 0 && fr < 4000) o.x = (_Float16)Hg[fr * 65 + 64];
          *(f16x4*)&sHf[r * HF_STRIDE + 64] = o;     // k=64 + zeros 65..67
        } else {
          *(f16x4*)&sHf[r * HF_STRIDE + 68] = o;     // zeros k=68..71
        }
      }
    }
  }

  // ---------------- P0c: noise -> sXh REVERSED f16 (xr[u] = 2*noise[79-u]-1) --
  {
    const float* Ng = Ng_ + (size_t)b * 320000;
#pragma unroll
    for (int j = 0; j < 3; ++j) {
      int q = t + NT * j;
      if (q < NSLOT * 20) {
        int fi = q / 20, qm = q - 20 * fi;
        int fr = f0 - 2 + fi;
        f16x4 o = {(_Float16)0.f, (_Float16)0.f, (_Float16)0.f, (_Float16)0.f};
        if (fr >= 0 && fr < 4000) {
          float4 v = *(const float4*)&Ng[(size_t)fr * 80 + 4 * qm];
          o.x = (_Float16)(2.f * v.w - 1.f);   // x[4qm+3]
          o.y = (_Float16)(2.f * v.z - 1.f);   // x[4qm+2]
          o.z = (_Float16)(2.f * v.y - 1.f);   // x[4qm+1]
          o.w = (_Float16)(2.f * v.x - 1.f);   // x[4qm]
        }
        *(f16x4*)&sXh[fi * X_STRIDE + (76 - 4 * qm)] = o;   // 8B-aligned
      }
    }
  }
  __syncthreads();

  // ------- P1: firwin = H x M^T via MFMA 16x16x32 f16 (R6-proven layout) -------
  // A rows clamped to 34: rows>=35 produce only discarded C rows (frame>=NSLOT).
  // ks==2/quad>0 A-frags (k 72..95) read the zero stub: M rows k>=65 are zero,
  // so products vanish; stub avoids NaN garbage.
  {
    const int wv   = t >> 6;
    const int lane = t & 63;
    const int quad = lane >> 4;
    const int l15  = lane & 15;
#pragma unroll 1
    for (int tile = wv; tile < 27; tile += 4) {
      const int mt = tile / 9, nt = tile - 9 * (tile / 9);
      const int rr = mt * 16 + l15;
      const int row = (rr > 34) ? 34 : rr;
      f32x4 acc = {0.f, 0.f, 0.f, 0.f};
#pragma unroll
      for (int ks = 0; ks < 3; ++ks) {
        const _Float16* ap;
        if (ks == 2) ap = (quad > 0) ? &sHf[ZSTUB] : &sHf[row * HF_STRIDE + 64];
        else         ap = &sHf[row * HF_STRIDE + ks * 32 + quad * 8];
        f16x8 a = *(const f16x8*)ap;
        f16x8 bb = ((const f16x8*)Mg)[(nt * 3 + ks) * 64 + lane];
        acc = __builtin_amdgcn_mfma_f32_16x16x32_f16(a, bb, acc, 0, 0, 0);
      }
      const int n = nt * 16 + l15;
      const int fr0 = mt * 16 + quad * 4;
      if (n <= 128) {
#pragma unroll
        for (int r = 0; r < 4; ++r) {
          int frame = fr0 + r;
          if (frame < NSLOT) sWh[frame * W_STRIDE + W_P + n] = (_Float16)acc[r];
        }
      }
    }
  }
  __syncthreads();

  // ------- P2: gather convolution, 8-m-wide trips, reversed-x (no swaps) -------
  {
    const int col = t & 31;
    const int pb  = t >> 5;
    const int e   = 64 + 10 * pb;
    const int qq  = (e >= 80) ? 1 : 0;
    const int D   = e - 80 * qq;                    // per half-wave uniform, even
    float acc[10];
#pragma unroll
    for (int i = 0; i < 10; ++i) acc[i] = 0.f;

#pragma unroll 1
    for (int g = 2; g >= -1; --g) {                 // source frame F - g
      const int dlt = D + 80 * g;                   // even
      int Ulo = (dlt - 128) >> 3; if (Ulo < 0) Ulo = 0;
      int Uhi = (dlt + 9) >> 3;   if (Uhi > 9) Uhi = 9;
      if (Ulo > Uhi) continue;
      const int slot = col + qq - g + 2;            // 0..34
      const _Float16* wr = &sWh[slot * W_STRIDE];
      const _Float16* xr = &sXh[slot * X_STRIDE];
      int wb = W_P + dlt - 8 * Ulo - 4;             // even; running tap base

      // w-window: wEa[k] = (w[wb-4+2k], w[wb-4+2k+1]) even-aligned b32 loads,
      // wOa[k] = odd pair via alignbit. PAIR(K)=(wr[wb+K], wr[wb+K+1]),
      // K in [-3,13] used. All out-of-range taps land in zero pads.
      h2 wEa[10], wOa[9];
#pragma unroll
      for (int k2 = 0; k2 < 10; ++k2) wEa[k2] = *(const h2*)&wr[wb - 4 + 2 * k2];
#pragma unroll
      for (int k2 = 0; k2 < 9; ++k2) wOa[k2] = mid_h2(wEa[k2], wEa[k2 + 1]);

#define PAIRX(K) (((K) & 1) ? wOa[(((K) - 1) >> 1) + 2] : wEa[(((K) >> 1) + 2)])
#pragma unroll 4
      for (int U = Ulo; U <= Uhi; ++U) {
        // reversed rows: xr[u]=x[79-u] -> aligned b64s give descending pairs free
        const _Float16* xp = &xr[72 - 8 * U];
        f16x4 q0 = *(const f16x4*)&xp[0];           // (x7,x6,x5,x4) of m=8U+..
        f16x4 q1 = *(const f16x4*)&xp[4];           // (x3,x2,x1,x0)
        h2 xD; xD.x = q0.x; xD.y = q0.y;            // (x7,x6) — reg halves, free
        h2 xC; xC.x = q0.z; xC.y = q0.w;            // (x5,x4)
        h2 xB; xB.x = q1.x; xB.y = q1.y;            // (x3,x2)
        h2 xA; xA.x = q1.z; xA.y = q1.w;            // (x1,x0)
#pragma unroll
        for (int i = 0; i < 10; ++i) {
          float a = acc[i];
          a = __builtin_amdgcn_fdot2(xA, PAIRX(i + 3), a, false);  // m 8U+0,1
          a = __builtin_amdgcn_fdot2(xB, PAIRX(i + 1), a, false);  // m 8U+2,3
          a = __builtin_amdgcn_fdot2(xC, PAIRX(i - 1), a, false);  // m 8U+4,5
          a = __builtin_amdgcn_fdot2(xD, PAIRX(i - 3), a, false);  // m 8U+6,7
          acc[i] = a;
        }
        // slide window down 8 f16 = 4 pair-slots; W_P=24 => wb-12 >= 0 always
        const _Float16* wp = &wr[wb - 12];
#pragma unroll
        for (int k2 = 9; k2 >= 4; --k2) wEa[k2] = wEa[k2 - 4];
#pragma unroll
        for (int k2 = 8; k2 >= 4; --k2) wOa[k2] = wOa[k2 - 4];
        wEa[0] = *(const h2*)&wp[0];
        wEa[1] = *(const h2*)&wp[2];
        wEa[2] = *(const h2*)&wp[4];
        wEa[3] = *(const h2*)&wp[6];
        wOa[0] = mid_h2(wEa[0], wEa[1]);
        wOa[1] = mid_h2(wEa[1], wEa[2]);
        wOa[2] = mid_h2(wEa[2], wEa[3]);
        wOa[3] = mid_h2(wEa[3], wEa[4]);
        wb -= 8;
      }
#undef PAIRX
    }

    // exactly-once writeout: u0 = 80*col + 10*pb (even -> float2 stores)
    float* Ob = Og_ + (size_t)b * 320000 + 2560 * bx + 80 * col + 10 * pb;
#pragma unroll
    for (int s = 0; s < 5; ++s) {
      float2 v; v.x = acc[2 * s]; v.y = acc[2 * s + 1];
      *(float2*)&Ob[2 * s] = v;
    }
  }
}

extern "C" void kernel_launch(void* const* d_in, const int* in_sizes, int n_in,
                              void* d_out, int out_size, void* d_ws, size_t ws_size,
                              hipStream_t stream) {
  const float* H     = (const float*)d_in[0];   // [32,4000,65] fp32
  const float* noise = (const float*)d_in[1];   // [32,4000,80] fp32
  float* out = (float*)d_out;                   // [32,320000] fp32
  _Float16* M = (_Float16*)d_ws;                // 27,648 B of scratch
  (void)in_sizes; (void)n_in; (void)ws_size; (void)out_size;

  minit_kernel<<<54, 256, 0, stream>>>(M);      // rebuilt every call (ws re-poisoned)
  dim3 grid(125, 32, 1);
  fng_kernel<<<grid, NT, 0, stream>>>(H, noise, out, M);
}